// Round 4
// baseline (189.511 us; speedup 1.0000x reference)
//
#include <hip/hip_runtime.h>
#include <hip/hip_bf16.h>

// HeadLayer: B=8, S=2048, E=1024, H=64.
// Inputs (fp32): x[B,S,E], Wq[E,H], Wk[E,H], Wv[E,H]. Output (fp32): [B,S,H].
// ws: qb[B,S,H] bf16 (pre-scaled 1/32), kb[B,S,H] bf16, vtb[B,H,S] bf16,
//     Wd frag-direct W layout (bf16), pacc[B,S,8,H] fp32, plsum[B,S,8] fp32.

#define BATCH 8
#define SEQ   2048
#define EMB   1024
#define HD    64
#define ROWS  (BATCH*SEQ)      // 16384
#define BK    64
#define NKT   (EMB / BK)       // 16
#define NSPLIT 8

typedef __attribute__((ext_vector_type(8))) short short8;   // 8 bf16 (4 VGPR)
typedef __attribute__((ext_vector_type(4))) float floatx4;  // MFMA C/D frag

static __device__ __forceinline__ short f2bf(float f) {
  union { __hip_bfloat16 h; short s; } u;
  u.h = __float2bfloat16(f);
  return u.s;
}

static __device__ __forceinline__ short8 pack8(float4 u, float4 v) {
  short8 r;
  r[0] = f2bf(u.x); r[1] = f2bf(u.y); r[2] = f2bf(u.z); r[3] = f2bf(u.w);
  r[4] = f2bf(v.x); r[5] = f2bf(v.y); r[6] = f2bf(v.z); r[7] = f2bf(v.w);
  return r;
}

// ---------------- W pre-pass: frag-direct layout (unchanged, verified) ------
__global__ __launch_bounds__(256) void wt_kernel(
    const float* __restrict__ Wq, const float* __restrict__ Wk,
    const float* __restrict__ Wv, short* __restrict__ Wd) {
  const int id = blockIdx.x * 256 + threadIdx.x;   // 0..24575
  const int lane = id & 63;
  const int ks = (id >> 6) & 1;
  const int id2 = id >> 7;                          // kt*12 + nt
  const int nt = id2 % 12;
  const int kt = id2 / 12;
  const int lo = lane & 15, quad = lane >> 4;
  const int np = nt * 16 + lo;
  const float* __restrict__ W = (np < 64) ? Wq : ((np < 128) ? Wk : Wv);
  const int n = np & 63;
  const int k0 = kt * BK + (4 * ks + quad) * 8;
  short8 o;
#pragma unroll
  for (int u = 0; u < 8; ++u) o[u] = f2bf(W[(size_t)(k0 + u) * HD + n]);
  *(short8*)(Wd + (size_t)id * 8) = o;
}

// ---------------- MFMA QKV projection (unchanged from R2, verified) ---------
__global__ __launch_bounds__(256, 2) void proj_kernel(
    const float* __restrict__ x, const short* __restrict__ Wd,
    short* __restrict__ qb, short* __restrict__ kb_, short* __restrict__ vtb) {
  __shared__ __align__(16) short Ab[2][32 * 64];   // 8 KB bf16, XOR-swizzled

  const int t = threadIdx.x, lane = t & 63, w = t >> 6;
  const int lo = lane & 15, quad = lane >> 4;
  const int e = lo & 7;
  const int m0 = blockIdx.x * 32;

  const int srow = t >> 3, sc = t & 7;
  const float* sgp = x + (size_t)(m0 + srow) * EMB + sc * 8;
  const int sslot = srow * 64 + ((sc ^ (srow & 7)) << 3);

  const short* bgp = Wd + (size_t)(w * 3) * 1024 + lane * 8;

  floatx4 acc[2][3];
#pragma unroll
  for (int mf = 0; mf < 2; ++mf)
#pragma unroll
    for (int j = 0; j < 3; ++j) acc[mf][j] = (floatx4){0.f, 0.f, 0.f, 0.f};

  short8 bcur[3][2], bnxt[3][2];
  float4 ra, rb;

  auto LOADA = [&](int kt) {
    const float* p = sgp + kt * BK;
    ra = *(const float4*)(p);
    rb = *(const float4*)(p + 4);
  };
  auto LOAD_B = [&](short8 (&bf)[3][2], int kt) {
    const short* bg = bgp + (size_t)kt * 12288;
#pragma unroll
    for (int j = 0; j < 3; ++j)
#pragma unroll
      for (int ks = 0; ks < 2; ++ks)
        bf[j][ks] = *(const short8*)(bg + j * 1024 + ks * 512);
  };

  LOADA(0);
  LOAD_B(bcur, 0);
  *(short8*)(&Ab[0][sslot]) = pack8(ra, rb);
  __syncthreads();

  int buf = 0;
  for (int kt = 0; kt < NKT; ++kt) {
    const bool more = (kt + 1 < NKT);
    if (more) { LOADA(kt + 1); LOAD_B(bnxt, kt + 1); }
    short8 af[2][2];
#pragma unroll
    for (int mf = 0; mf < 2; ++mf)
#pragma unroll
      for (int ks = 0; ks < 2; ++ks)
        af[mf][ks] = *(const short8*)(
            &Ab[buf][(mf * 16 + lo) * 64 + (((4 * ks + quad) ^ e) << 3)]);
#pragma unroll
    for (int ks = 0; ks < 2; ++ks)
#pragma unroll
      for (int j = 0; j < 3; ++j) {
        acc[0][j] = __builtin_amdgcn_mfma_f32_16x16x32_bf16(af[0][ks], bcur[j][ks], acc[0][j], 0, 0, 0);
        acc[1][j] = __builtin_amdgcn_mfma_f32_16x16x32_bf16(af[1][ks], bcur[j][ks], acc[1][j], 0, 0, 0);
      }
    if (more) {
      *(short8*)(&Ab[buf ^ 1][sslot]) = pack8(ra, rb);
#pragma unroll
      for (int j = 0; j < 3; ++j)
#pragma unroll
        for (int ks = 0; ks < 2; ++ks) bcur[j][ks] = bnxt[j][ks];
    }
    __syncthreads();
    buf ^= 1;
  }

  const int bb = m0 >> 11;
  const int sbase = (m0 & (SEQ - 1)) + quad * 4;
#pragma unroll
  for (int mf = 0; mf < 2; ++mf) {
    const int rowb = m0 + mf * 16 + quad * 4;
#pragma unroll
    for (int j = 0; j < 3; ++j) {
      const int nt = w * 3 + j;
      const floatx4 v = acc[mf][j];
      if (nt < 4) {
#pragma unroll
        for (int r = 0; r < 4; ++r)
          qb[(size_t)(rowb + r) * HD + nt * 16 + lo] = f2bf(v[r] * 0.03125f);
      } else if (nt < 8) {
#pragma unroll
        for (int r = 0; r < 4; ++r)
          kb_[(size_t)(rowb + r) * HD + (nt - 4) * 16 + lo] = f2bf(v[r]);
      } else {
        const int col = (nt - 8) * 16 + lo;
        short4 sv = make_short4(f2bf(v[0]), f2bf(v[1]), f2bf(v[2]), f2bf(v[3]));
        *(short4*)(vtb + ((size_t)bb * HD + col) * SEQ + sbase + mf * 16) = sv;
      }
    }
  }
}

// ---------------- flash attention: 64-row q-block x split, LDS-staged K/V ---
// Block = 4 waves x 16 q-rows (64-row q-block), one split sp; all 4 waves
// consume the SAME 32-key tile -> cooperative coalesced LDS staging (layouts
// from the verified R0 kernel: KSTR=72, VSTR=36). Register prefetch of next
// tile overlaps compute; 2 barriers/step. Grid 32qb x 8sp x 8b = 2048 blocks
// -> 8 blocks/CU = 32 waves/CU. Heavy qb first; b = gx&7 pins batch to XCD.
#define PSTR 40
#define KSTR 72
#define VSTR 36

__global__ __launch_bounds__(256, 8) void attn_kernel(
    const short* __restrict__ qb, const short* __restrict__ kb,
    const short* __restrict__ vtb, float* __restrict__ pacc,
    float* __restrict__ plsum) {
  __shared__ __align__(16) short Ks[32 * KSTR];      // 4.6 KB
  __shared__ __align__(16) short Vs[64 * VSTR];      // 4.6 KB
  __shared__ __align__(16) short Ps[4][16 * PSTR];   // 5.1 KB, per-wave

  const int gx = blockIdx.x;                 // 0..2047
  const int qbi = 31 - (gx >> 6);            // heavy first
  const int sp = (gx >> 3) & 7;
  const int b = gx & 7;
  const int Q0 = qbi * 64;
  const int niter = qbi * 2 + 2;             // 32-key tiles covering 0..Q0+63

  const int t = threadIdx.x, lane = t & 63, w = t >> 6;
  const int lo = lane & 15, quad = lane >> 4;
  const int q0w = Q0 + w * 16;

  // Q frags: rows q0w+lo, k-chunks quad*8 (+32)
  const short* qp = qb + ((size_t)b * SEQ + q0w + lo) * HD + quad * 8;
  const short8 qf0 = *(const short8*)(qp);
  const short8 qf1 = *(const short8*)(qp + 32);

  const short* __restrict__ kgb = kb + (size_t)b * SEQ * HD;
  const short* __restrict__ vgb = vtb + (size_t)b * HD * SEQ;

  // cooperative staging addresses (coalesced): K row=key t>>3, V row=h t>>2
  const int skey = t >> 3, sch = t & 7;
  const short* kgp = kgb + (size_t)skey * HD + sch * 8;   // + j0*HD
  short* kls = Ks + skey * KSTR + sch * 8;
  const int svh = t >> 2, svc = t & 3;
  const short* vgp = vgb + (size_t)svh * SEQ + svc * 8;   // + j0
  short* vls = Vs + svh * VSTR + svc * 8;

  floatx4 acc[4];
  float lsum[4] = {0.f, 0.f, 0.f, 0.f};
#pragma unroll
  for (int nt = 0; nt < 4; ++nt) acc[nt] = (floatx4){0.f, 0.f, 0.f, 0.f};

  short* Pw = Ps[w];
  const int rowq = q0w + quad * 4;

  int it = sp;
  if (it < niter) {
    const int j0 = it * 32;
    *(short8*)kls = *(const short8*)(kgp + (size_t)j0 * HD);
    *(short8*)vls = *(const short8*)(vgp + j0);
  }
  __syncthreads();

  for (; it < niter; it += NSPLIT) {
    const int j0 = it * 32;
    // ---- frag reads from LDS (keys 0..31 of this tile)
    short8 kf[2][2], vf[4];
#pragma unroll
    for (int n2 = 0; n2 < 2; ++n2) {
      const short* kr = &Ks[(n2 * 16 + lo) * KSTR + quad * 8];
      kf[n2][0] = *(const short8*)(kr);
      kf[n2][1] = *(const short8*)(kr + 32);
    }
#pragma unroll
    for (int nt = 0; nt < 4; ++nt)
      vf[nt] = *(const short8*)(&Vs[(nt * 16 + lo) * VSTR + quad * 8]);

    // ---- prefetch next tile into regs (consumed by ds_write after barrier)
    const bool more = (it + NSPLIT < niter);
    short8 knx, vnx;
    if (more) {
      const int jn = j0 + NSPLIT * 32;
      knx = *(const short8*)(kgp + (size_t)jn * HD);
      vnx = *(const short8*)(vgp + jn);
    }

    // ---- QK^T
    floatx4 s0 = (floatx4){0.f, 0.f, 0.f, 0.f};
    floatx4 s1 = (floatx4){0.f, 0.f, 0.f, 0.f};
    __builtin_amdgcn_s_setprio(1);
    s0 = __builtin_amdgcn_mfma_f32_16x16x32_bf16(qf0, kf[0][0], s0, 0, 0, 0);
    s0 = __builtin_amdgcn_mfma_f32_16x16x32_bf16(qf1, kf[0][1], s0, 0, 0, 0);
    s1 = __builtin_amdgcn_mfma_f32_16x16x32_bf16(qf0, kf[1][0], s1, 0, 0, 0);
    s1 = __builtin_amdgcn_mfma_f32_16x16x32_bf16(qf1, kf[1][1], s1, 0, 0, 0);
    __builtin_amdgcn_s_setprio(0);

    // ---- softmax numerator + P to per-wave LDS
    const bool diag = (j0 + 32 > q0w);
#pragma unroll
    for (int r = 0; r < 4; ++r) {
      float e0 = __expf(s0[r]);
      float e1 = __expf(s1[r]);
      if (diag) {
        e0 = (j0 + lo <= rowq + r) ? e0 : 0.f;
        e1 = (j0 + 16 + lo <= rowq + r) ? e1 : 0.f;
      }
      lsum[r] += e0 + e1;
      Pw[(quad * 4 + r) * PSTR + lo] = f2bf(e0);
      Pw[(quad * 4 + r) * PSTR + 16 + lo] = f2bf(e1);
    }
    const short8 pf = *(const short8*)(&Pw[lo * PSTR + quad * 8]);
    // ---- P·V
    __builtin_amdgcn_s_setprio(1);
#pragma unroll
    for (int nt = 0; nt < 4; ++nt)
      acc[nt] = __builtin_amdgcn_mfma_f32_16x16x32_bf16(pf, vf[nt], acc[nt], 0, 0, 0);
    __builtin_amdgcn_s_setprio(0);

    __syncthreads();   // all waves' frag reads done; prev staging consumed
    if (more) {
      *(short8*)kls = knx;
      *(short8*)vls = vnx;
    }
    __syncthreads();   // staging visible
  }

  // row-sum over the 16 key lanes (lo bits only; quad carries q)
#pragma unroll
  for (int d = 1; d < 16; d <<= 1) {
#pragma unroll
    for (int r = 0; r < 4; ++r) lsum[r] += __shfl_xor(lsum[r], d);
  }

  // un-normalized partials out (zeros for empty splits)
#pragma unroll
  for (int nt = 0; nt < 4; ++nt) {
#pragma unroll
    for (int r = 0; r < 4; ++r)
      pacc[(((size_t)b * SEQ + rowq + r) * NSPLIT + sp) * HD + nt * 16 + lo] =
          acc[nt][r];
  }
  if (lo == 0) {
#pragma unroll
    for (int r = 0; r < 4; ++r)
      plsum[((size_t)b * SEQ + rowq + r) * NSPLIT + sp] = lsum[r];
  }
}

// ---------------- combine: out = sum(pacc)/sum(plsum) -----------------------
__global__ __launch_bounds__(256) void comb_kernel(
    const float* __restrict__ pacc, const float* __restrict__ plsum,
    float* __restrict__ out) {
  const int idx = blockIdx.x * 256 + threadIdx.x;   // 0 .. ROWS*16-1
  const int row = idx >> 4;
  const int h4 = (idx & 15) << 2;
  const float* pa = pacc + (size_t)row * (NSPLIT * HD) + h4;
  float4 s = make_float4(0.f, 0.f, 0.f, 0.f);
  float d = 0.f;
#pragma unroll
  for (int sp = 0; sp < NSPLIT; ++sp) {
    const float4 v = *(const float4*)(pa + sp * HD);
    s.x += v.x; s.y += v.y; s.z += v.z; s.w += v.w;
    d += plsum[(size_t)row * NSPLIT + sp];
  }
  const float inv = 1.0f / d;
  float4 o = make_float4(s.x * inv, s.y * inv, s.z * inv, s.w * inv);
  *(float4*)(out + (size_t)row * HD + h4) = o;
}

extern "C" void kernel_launch(void* const* d_in, const int* in_sizes, int n_in,
                              void* d_out, int out_size, void* d_ws, size_t ws_size,
                              hipStream_t stream) {
  const float* x  = (const float*)d_in[0];
  const float* Wq = (const float*)d_in[1];
  const float* Wk = (const float*)d_in[2];
  const float* Wv = (const float*)d_in[3];
  float* out = (float*)d_out;
  short* ws = (short*)d_ws;
  short* qbp = ws;
  short* kbp = ws + (size_t)ROWS * HD;
  short* vtp = ws + (size_t)2 * ROWS * HD;
  short* Wd  = ws + (size_t)3 * ROWS * HD;          // 24576*8 shorts (384 KB)
  float* pacc  = (float*)(ws + (size_t)3 * ROWS * HD + 196608);  // 33.6 MB
  float* plsum = pacc + (size_t)ROWS * NSPLIT * HD;              // 512 KB

  wt_kernel<<<dim3(96), 256, 0, stream>>>(Wq, Wk, Wv, Wd);
  proj_kernel<<<dim3(ROWS / 32), 256, 0, stream>>>(x, Wd, qbp, kbp, vtp);
  attn_kernel<<<dim3(32 * NSPLIT * BATCH), 256, 0, stream>>>(qbp, kbp, vtp, pacc, plsum);
  comb_kernel<<<dim3(ROWS * 16 / 256), 256, 0, stream>>>(pacc, plsum, out);
}

// Round 5
// 169.396 us; speedup vs baseline: 1.1187x; 1.1187x over previous
//
#include <hip/hip_runtime.h>
#include <hip/hip_bf16.h>

// HeadLayer: B=8, S=2048, E=1024, H=64.
// Inputs (fp32): x[B,S,E], Wq[E,H], Wk[E,H], Wv[E,H]. Output (fp32): [B,S,H].
// ws: qb[B,S,H] bf16 (pre-scaled 1/32), kb[B,S,H] bf16, vtb[B,H,S] bf16,
//     Wd frag-direct W layout (bf16), pacc[B,S,4,H] fp32, plsum[B,S,4] fp32.

#define BATCH 8
#define SEQ   2048
#define EMB   1024
#define HD    64
#define ROWS  (BATCH*SEQ)      // 16384
#define BK    64
#define NKT   (EMB / BK)       // 16
#define NSPLIT 4

typedef __attribute__((ext_vector_type(8))) short short8;   // 8 bf16 (4 VGPR)
typedef __attribute__((ext_vector_type(4))) float floatx4;  // MFMA C/D frag

static __device__ __forceinline__ short f2bf(float f) {
  union { __hip_bfloat16 h; short s; } u;
  u.h = __float2bfloat16(f);
  return u.s;
}

// ---------------- W pre-pass: frag-direct layout (unchanged, verified) ------
// Wd slot id = ((kt*12 + nt)*2 + ks)*64 + lane, holding short8:
//   value[u] = W_logical[nt*16 + (lane&15)][kt*64 + (4*ks + (lane>>4))*8 + u]
__global__ __launch_bounds__(256) void wt_kernel(
    const float* __restrict__ Wq, const float* __restrict__ Wk,
    const float* __restrict__ Wv, short* __restrict__ Wd) {
  const int id = blockIdx.x * 256 + threadIdx.x;   // 0..24575
  const int lane = id & 63;
  const int ks = (id >> 6) & 1;
  const int id2 = id >> 7;                          // kt*12 + nt
  const int nt = id2 % 12;
  const int kt = id2 / 12;
  const int lo = lane & 15, quad = lane >> 4;
  const int np = nt * 16 + lo;
  const float* __restrict__ W = (np < 64) ? Wq : ((np < 128) ? Wk : Wv);
  const int n = np & 63;
  const int k0 = kt * BK + (4 * ks + quad) * 8;
  short8 o;
#pragma unroll
  for (int u = 0; u < 8; ++u) o[u] = f2bf(W[(size_t)(k0 + u) * HD + n]);
  *(short8*)(Wd + (size_t)id * 8) = o;
}

// ---------------- MFMA QKV projection: M=16 tiles, 1024 blocks --------------
// 4 blocks/CU = 16 waves/CU (TLP x2 vs M=32). Per kt: prefetch A(kt+1) float4
// + B(kt+1) regs; ds_read A frags (bf16, XOR-swizzled) + 6 MFMA/wave;
// convert+ds_write A(kt+1); 1 barrier/kt. A-tile 16x64 bf16 = 2.25 KB/buf.
#define AST 72   // A-tile row stride in shorts (64 + 8 pad)

__global__ __launch_bounds__(256, 4) void proj_kernel(
    const float* __restrict__ x, const short* __restrict__ Wd,
    short* __restrict__ qb, short* __restrict__ kb_, short* __restrict__ vtb) {
  __shared__ __align__(16) short Ab[2][16 * AST];   // 4.5 KB

  const int t = threadIdx.x, lane = t & 63, w = t >> 6;
  const int lo = lane & 15, quad = lane >> 4;
  const int m0 = blockIdx.x * 16;

  // staging: thread -> (row = t>>4, chunk c = t&15 of 4 floats); slot = c ^ ((row&7)<<1)
  const int srow = t >> 4, sc = t & 15;
  const float* sgp = x + (size_t)(m0 + srow) * EMB + sc * 4;
  const int sslot = srow * AST + (sc ^ ((srow & 7) << 1)) * 4;

  const short* bgp = Wd + (size_t)(w * 3) * 1024 + lane * 8;

  floatx4 acc[3];
#pragma unroll
  for (int j = 0; j < 3; ++j) acc[j] = (floatx4){0.f, 0.f, 0.f, 0.f};

  short8 bcur[3][2], bnxt[3][2];
  float4 ra;

  auto LOADA = [&](int kt) { ra = *(const float4*)(sgp + kt * BK); };
  auto WRA = [&](int buf) {
    short4 s = make_short4(f2bf(ra.x), f2bf(ra.y), f2bf(ra.z), f2bf(ra.w));
    *(short4*)(&Ab[buf][sslot]) = s;
  };
  auto LOAD_B = [&](short8 (&bf)[3][2], int kt) {
    const short* bg = bgp + (size_t)kt * 12288;
#pragma unroll
    for (int j = 0; j < 3; ++j)
#pragma unroll
      for (int ks = 0; ks < 2; ++ks)
        bf[j][ks] = *(const short8*)(bg + j * 1024 + ks * 512);
  };

  LOADA(0);
  LOAD_B(bcur, 0);
  WRA(0);
  __syncthreads();

  int buf = 0;
  for (int kt = 0; kt < NKT; ++kt) {
    const bool more = (kt + 1 < NKT);
    if (more) { LOADA(kt + 1); LOAD_B(bnxt, kt + 1); }
    // A frags: row lo, chunk pair (ks*8 + quad*2) ^ ((lo&7)<<1)
    short8 af[2];
#pragma unroll
    for (int ks = 0; ks < 2; ++ks)
      af[ks] = *(const short8*)(
          &Ab[buf][lo * AST + ((ks * 8 + quad * 2) ^ ((lo & 7) << 1)) * 4]);
#pragma unroll
    for (int ks = 0; ks < 2; ++ks)
#pragma unroll
      for (int j = 0; j < 3; ++j)
        acc[j] = __builtin_amdgcn_mfma_f32_16x16x32_bf16(af[ks], bcur[j][ks], acc[j], 0, 0, 0);
    if (more) {
      WRA(buf ^ 1);
#pragma unroll
      for (int j = 0; j < 3; ++j)
#pragma unroll
        for (int ks = 0; ks < 2; ++ks) bcur[j][ks] = bnxt[j][ks];
    }
    __syncthreads();
    buf ^= 1;
  }

  // ---- epilogue: wave-private n-tiles, direct stores (M=16)
  const int bb = m0 >> 11;
  const int sbase = (m0 & (SEQ - 1)) + quad * 4;
  const int rowb = m0 + quad * 4;
#pragma unroll
  for (int j = 0; j < 3; ++j) {
    const int nt = w * 3 + j;
    const floatx4 v = acc[j];
    if (nt < 4) {
#pragma unroll
      for (int r = 0; r < 4; ++r)
        qb[(size_t)(rowb + r) * HD + nt * 16 + lo] = f2bf(v[r] * 0.03125f);
    } else if (nt < 8) {
#pragma unroll
      for (int r = 0; r < 4; ++r)
        kb_[(size_t)(rowb + r) * HD + (nt - 4) * 16 + lo] = f2bf(v[r]);
    } else {
      const int col = (nt - 8) * 16 + lo;
      short4 sv = make_short4(f2bf(v[0]), f2bf(v[1]), f2bf(v[2]), f2bf(v[3]));
      *(short4*)(vtb + ((size_t)bb * HD + col) * SEQ + sbase) = sv;
    }
  }
}

// ---------------- flash attention: R3 structure + per-wave coalesced staging
// Wave task = (qt 16-row tile, batch, interleaved split sp: it = sp, sp+4,...),
// 32-key steps, zero barriers, heavy-first. NEW: each wave stages its K tile
// (4 KB contiguous -> 4 coalesced 1KB loads) and V^T tile (64x64B segments ->
// 4 coalesced loads) into PER-WAVE LDS (wave-synchronous), with register
// prefetch of the next tile overlapping QK/softmax/PV. Line-touches per step
// drop ~8x vs R3's direct gathers. LDS 42 KB -> 3 blocks/CU = 12 waves/CU.
#define PSTR 40
#define KSTR 72   // shorts per key row (64 + 8 pad)
#define VSTR 36   // shorts per h row (32 + 4 pad)

__global__ __launch_bounds__(256, 3) void attn_kernel(
    const short* __restrict__ qb, const short* __restrict__ kb,
    const short* __restrict__ vtb, float* __restrict__ pacc,
    float* __restrict__ plsum) {
  __shared__ __align__(16) short Ks[4][32 * KSTR];   // 4.6 KB/wave
  __shared__ __align__(16) short Vs[4][64 * VSTR];   // 4.6 KB/wave
  __shared__ __align__(16) short Ps[4][16 * PSTR];   // 1.25 KB/wave

  const int bx = blockIdx.x;                 // 0..1023
  const int qt = 127 - (bx >> 3);            // heavy first
  const int b = bx & 7;
  const int w = threadIdx.x >> 6;
  const int sp = w;                          // split = wave
  const int lane = threadIdx.x & 63;
  const int lo = lane & 15, quad = lane >> 4;
  const int q0 = qt * 16;
  const int niter = (qt >> 1) + 1;           // 32-key steps

  // Q frags: rows q0+lo, k-chunks quad*8 (+32)
  const short* qp = qb + ((size_t)b * SEQ + q0 + lo) * HD + quad * 8;
  const short8 qf0 = *(const short8*)(qp);
  const short8 qf1 = *(const short8*)(qp + 32);

  const short* __restrict__ kgb = kb + (size_t)b * SEQ * HD;
  const short* __restrict__ vgb = vtb + (size_t)b * HD * SEQ;

  short* Ksw = Ps[0] ? Ks[w] : Ks[w];   // per-wave LDS regions
  short* Vsw = Vs[w];
  short* Pw  = Ps[w];
  Ksw = Ks[w];

  // staging addresses (lane-constant parts)
  const short* kgl = kgb + lane * 8;                               // + j0*HD + i*512
  const short* vgl = vgb + (size_t)(lane >> 2) * SEQ + (lane & 3) * 8;  // + i*16*SEQ + j0
  short* klds = &Ksw[(lane >> 3) * KSTR + (lane & 7) * 8];         // + i*8*KSTR
  short* vlds = &Vsw[(lane >> 2) * VSTR + (lane & 3) * 8];         // + i*16*VSTR

  floatx4 acc[4];
  float lsum[4] = {0.f, 0.f, 0.f, 0.f};
#pragma unroll
  for (int nt = 0; nt < 4; ++nt) acc[nt] = (floatx4){0.f, 0.f, 0.f, 0.f};

  const int rowq = q0 + quad * 4;

  short8 kpre[4], vpre[4];
  auto PRE = [&](int j0) {
#pragma unroll
    for (int i = 0; i < 4; ++i)
      kpre[i] = *(const short8*)(kgl + (size_t)j0 * HD + i * 512);
#pragma unroll
    for (int i = 0; i < 4; ++i)
      vpre[i] = *(const short8*)(vgl + (size_t)i * 16 * SEQ + j0);
  };
  auto WR = [&]() {
#pragma unroll
    for (int i = 0; i < 4; ++i) *(short8*)(klds + i * 8 * KSTR) = kpre[i];
#pragma unroll
    for (int i = 0; i < 4; ++i) *(short8*)(vlds + i * 16 * VSTR) = vpre[i];
  };

  int it = sp;
  if (it < niter) { PRE(it * 32); WR(); }

  for (; it < niter; it += NSPLIT) {
    const int j0 = it * 32;
    // ---- frag reads from per-wave LDS
    short8 kf[2][2], vf[4];
#pragma unroll
    for (int n2 = 0; n2 < 2; ++n2) {
      const short* kr = &Ksw[(n2 * 16 + lo) * KSTR + quad * 8];
      kf[n2][0] = *(const short8*)(kr);
      kf[n2][1] = *(const short8*)(kr + 32);
    }
#pragma unroll
    for (int nt = 0; nt < 4; ++nt)
      vf[nt] = *(const short8*)(&Vsw[(nt * 16 + lo) * VSTR + quad * 8]);

    // ---- prefetch next tile into regs (overlaps QK/softmax/PV)
    const bool more = (it + NSPLIT < niter);
    if (more) PRE(j0 + NSPLIT * 32);

    // ---- QK^T
    floatx4 s0 = (floatx4){0.f, 0.f, 0.f, 0.f};
    floatx4 s1 = (floatx4){0.f, 0.f, 0.f, 0.f};
    __builtin_amdgcn_s_setprio(1);
    s0 = __builtin_amdgcn_mfma_f32_16x16x32_bf16(qf0, kf[0][0], s0, 0, 0, 0);
    s0 = __builtin_amdgcn_mfma_f32_16x16x32_bf16(qf1, kf[0][1], s0, 0, 0, 0);
    s1 = __builtin_amdgcn_mfma_f32_16x16x32_bf16(qf0, kf[1][0], s1, 0, 0, 0);
    s1 = __builtin_amdgcn_mfma_f32_16x16x32_bf16(qf1, kf[1][1], s1, 0, 0, 0);
    __builtin_amdgcn_s_setprio(0);

    // ---- softmax numerator + P to per-wave LDS
    const bool diag = (j0 + 32 > q0);
#pragma unroll
    for (int r = 0; r < 4; ++r) {
      float e0 = __expf(s0[r]);
      float e1 = __expf(s1[r]);
      if (diag) {
        e0 = (j0 + lo <= rowq + r) ? e0 : 0.f;
        e1 = (j0 + 16 + lo <= rowq + r) ? e1 : 0.f;
      }
      lsum[r] += e0 + e1;
      Pw[(quad * 4 + r) * PSTR + lo] = f2bf(e0);
      Pw[(quad * 4 + r) * PSTR + 16 + lo] = f2bf(e1);
    }
    const short8 pf = *(const short8*)(&Pw[lo * PSTR + quad * 8]);
    // ---- P·V
    __builtin_amdgcn_s_setprio(1);
#pragma unroll
    for (int nt = 0; nt < 4; ++nt)
      acc[nt] = __builtin_amdgcn_mfma_f32_16x16x32_bf16(pf, vf[nt], acc[nt], 0, 0, 0);
    __builtin_amdgcn_s_setprio(0);

    // ---- write prefetched tile to per-wave LDS (wave-synchronous)
    if (more) WR();
  }

  // row-sum over the 16 key lanes (lo bits only; quad carries q)
#pragma unroll
  for (int d = 1; d < 16; d <<= 1) {
#pragma unroll
    for (int r = 0; r < 4; ++r) lsum[r] += __shfl_xor(lsum[r], d);
  }

  // un-normalized partials out (zeros for empty splits)
#pragma unroll
  for (int nt = 0; nt < 4; ++nt) {
#pragma unroll
    for (int r = 0; r < 4; ++r)
      pacc[(((size_t)b * SEQ + rowq + r) * NSPLIT + sp) * HD + nt * 16 + lo] =
          acc[nt][r];
  }
  if (lo == 0) {
#pragma unroll
    for (int r = 0; r < 4; ++r)
      plsum[((size_t)b * SEQ + rowq + r) * NSPLIT + sp] = lsum[r];
  }
}

// ---------------- combine: out = sum(pacc)/sum(plsum) -----------------------
__global__ __launch_bounds__(256) void comb_kernel(
    const float* __restrict__ pacc, const float* __restrict__ plsum,
    float* __restrict__ out) {
  const int idx = blockIdx.x * 256 + threadIdx.x;   // 0 .. ROWS*16-1
  const int row = idx >> 4;
  const int h4 = (idx & 15) << 2;
  const float* pa = pacc + (size_t)row * (NSPLIT * HD) + h4;
  float4 s = make_float4(0.f, 0.f, 0.f, 0.f);
  float d = 0.f;
#pragma unroll
  for (int sp = 0; sp < NSPLIT; ++sp) {
    const float4 v = *(const float4*)(pa + sp * HD);
    s.x += v.x; s.y += v.y; s.z += v.z; s.w += v.w;
    d += plsum[(size_t)row * NSPLIT + sp];
  }
  const float inv = 1.0f / d;
  float4 o = make_float4(s.x * inv, s.y * inv, s.z * inv, s.w * inv);
  *(float4*)(out + (size_t)row * HD + h4) = o;
}

extern "C" void kernel_launch(void* const* d_in, const int* in_sizes, int n_in,
                              void* d_out, int out_size, void* d_ws, size_t ws_size,
                              hipStream_t stream) {
  const float* x  = (const float*)d_in[0];
  const float* Wq = (const float*)d_in[1];
  const float* Wk = (const float*)d_in[2];
  const float* Wv = (const float*)d_in[3];
  float* out = (float*)d_out;
  short* ws = (short*)d_ws;
  short* qbp = ws;
  short* kbp = ws + (size_t)ROWS * HD;
  short* vtp = ws + (size_t)2 * ROWS * HD;
  short* Wd  = ws + (size_t)3 * ROWS * HD;          // 24576*8 shorts (384 KB)
  float* pacc  = (float*)(ws + (size_t)3 * ROWS * HD + 196608);  // 16.8 MB
  float* plsum = pacc + (size_t)ROWS * NSPLIT * HD;              // 256 KB

  wt_kernel<<<dim3(96), 256, 0, stream>>>(Wq, Wk, Wv, Wd);
  proj_kernel<<<dim3(ROWS / 16), 256, 0, stream>>>(x, Wd, qbp, kbp, vtp);
  attn_kernel<<<dim3(128 * 8), 256, 0, stream>>>(qbp, kbp, vtp, pacc, plsum);
  comb_kernel<<<dim3(ROWS * 16 / 256), 256, 0, stream>>>(pacc, plsum, out);
}